// Round 8
// baseline (355.102 us; speedup 1.0000x reference)
//
#include <hip/hip_runtime.h>
#include <hip/hip_bf16.h>

typedef __attribute__((ext_vector_type(8))) short bf16x8;
typedef __attribute__((ext_vector_type(16))) float f32x16;

#define GLOBAL_CAST(p) (const __attribute__((address_space(1))) void*)(p)
#define LDS_CAST(p)    (__attribute__((address_space(3))) void*)(p)

static __device__ __forceinline__ unsigned short f2bf(float f) {
    union { float f; unsigned int u; } v; v.f = f;
    unsigned int u = v.u;
    unsigned int r = (u + 0x7FFFu + ((u >> 16) & 1u)) >> 16;   // RNE
    return (unsigned short)r;
}

// ---------------------------------------------------------------------------
// Kernel 1: per-row scale = max(mean(|w|), eps); q = ternary(w) as bf16 bits.
// ---------------------------------------------------------------------------
__global__ __launch_bounds__(256) void scale_quant_kernel(
    const float* __restrict__ w, float* __restrict__ scale,
    unsigned short* __restrict__ q, int K)
{
    const int row = blockIdx.x;
    const int tid = threadIdx.x;
    const float* wrow = w + (size_t)row * K;

    float s = 0.f;
    const int nvec = K >> 2;
    const float4* wv = (const float4*)wrow;
    for (int i = tid; i < nvec; i += blockDim.x) {
        float4 v = wv[i];
        s += fabsf(v.x) + fabsf(v.y) + fabsf(v.z) + fabsf(v.w);
    }
    #pragma unroll
    for (int off = 32; off > 0; off >>= 1) s += __shfl_down(s, off);

    __shared__ float red[4];
    const int lane = tid & 63, wid = tid >> 6;
    if (lane == 0) red[wid] = s;
    __syncthreads();
    const float total = red[0] + red[1] + red[2] + red[3];
    const float sc = fmaxf(total / (float)K, 1e-6f);
    const float thr = sc * 0.75f;
    if (tid == 0) scale[row] = sc;

    if (q != nullptr) {
        ushort4* qv = (ushort4*)(q + (size_t)row * K);
        for (int i = tid; i < nvec; i += blockDim.x) {
            float4 v = wv[i];
            ushort4 o;
            o.x = (v.x >= thr) ? 0x3F80u : ((v.x <= -thr) ? 0xBF80u : 0u);
            o.y = (v.y >= thr) ? 0x3F80u : ((v.y <= -thr) ? 0xBF80u : 0u);
            o.z = (v.z >= thr) ? 0x3F80u : ((v.z <= -thr) ? 0xBF80u : 0u);
            o.w = (v.w >= thr) ? 0x3F80u : ((v.w <= -thr) ? 0xBF80u : 0u);
            qv[i] = o;
        }
    }
}

// ---------------------------------------------------------------------------
// Kernel 2: x fp32 -> bf16 (RNE), 8 elems/thread.
// ---------------------------------------------------------------------------
__global__ __launch_bounds__(256) void convert_x_kernel(
    const float* __restrict__ x, unsigned short* __restrict__ xb, long n)
{
    long i = ((long)blockIdx.x * blockDim.x + threadIdx.x) * 8;
    if (i + 8 > n) return;
    float4 a = *(const float4*)(x + i);
    float4 b = *(const float4*)(x + i + 4);
    ushort4 lo, hi;
    lo.x = f2bf(a.x); lo.y = f2bf(a.y); lo.z = f2bf(a.z); lo.w = f2bf(a.w);
    hi.x = f2bf(b.x); hi.y = f2bf(b.y); hi.z = f2bf(b.z); hi.w = f2bf(b.w);
    *(ushort4*)(xb + i)     = lo;
    *(ushort4*)(xb + i + 4) = hi;
}

// ---------------------------------------------------------------------------
// Kernel 3: 128x128 bf16 GEMM, 32x32x16 MFMA, 2 blocks/CU (64 KiB LDS).
//   out[m][n] = scale[n] * sum_k Xb[m][k]*Qb[n][k] + bias[n]
// 256 thr = 4 waves (2M x 2N); per-wave 64x64 out = acc[2][2] 32x32 frags,
// K-tile (64) consumed as 4 k-slices of 16.
// LDS 64 KiB: 2 dbuf x {A 128x64, B 128x64} bf16 (16 KiB each).
// Rationale: all 1-block/CU 256^2 variants (r2-r7) idle ~30% at the tile-end
// drain+barrier. Two co-resident blocks = independent barrier domains; one
// block's drain overlaps the other's MFMA+ds_read (m114 co-scheduling).
// Chunk swizzle (both sides): slot s of row r holds global chunk s ^ m(r),
//   m(r) = (r&7) ^ ((r>>3)&7)  -- 0 bank conflicts (verified r7).
// Per K-tile t: sec A { stage A(t+1)->ta | ks0 rd+4 MFMA |
//                       stage B(t+1)->ta | ks1 rd+4 MFMA } bar
//               sec B { ks2 rd+4 MFMA | ks3 rd+4 MFMA } vmcnt(0) bar
// Operand layout (32x32x16): lane holds row l&31, k=(l>>5)*8+i.
// C/D layout: col=lane&31, row=(reg&3)+8*(reg>>2)+4*(lane>>5)  [m74/m101].
// ---------------------------------------------------------------------------
#define BM 128
#define BN 128
#define BK 64

__global__ __launch_bounds__(256, 2) void gemm128_kernel(
    const unsigned short* __restrict__ Xb,   // [M][K] bf16 bits
    const unsigned short* __restrict__ Qb,   // [N][K] bf16 bits
    const float* __restrict__ scale,
    const float* __restrict__ bias,
    float* __restrict__ out, int M, int N, int K)
{
    __shared__ __align__(16) char lds[65536];

    const int tid  = threadIdx.x;
    const int lane = tid & 63;
    const int wid  = tid >> 6;       // 0..3
    const int wm   = wid >> 1;       // 0..1  (M half of tile)
    const int wn   = wid & 1;        // 0..1  (N half)
    const int l31  = lane & 31;

    // XCD-bijective swizzle (grid % 8 == 0 guaranteed by host gate)
    int bid = blockIdx.x;
    const int nwg = gridDim.x;
    if ((nwg & 7) == 0) { const int cpx = nwg >> 3; bid = (bid & 7) * cpx + (bid >> 3); }
    const int nbn = N / BN;
    const int tm = bid / nbn, tn = bid % nbn;
    const int arow0 = tm * BM;
    const int brow0 = tn * BN;
    const int NT = K / BK;

    // ---- LDS read addressing: addr = (tb | base_with_m[frag]) ^ ksel[ks] ----
    // A buffer at tb, B at tb|0x4000; row stride 128 B; slot = chunk ^ m(row).
    const unsigned kgb = (unsigned)(((lane >> 5) & 1) << 4);
    unsigned ksel[4];
    #pragma unroll
    for (int ks = 0; ks < 4; ++ks) ksel[ks] = ((unsigned)ks << 5) | kgb;
    unsigned abx[2], bbx[2];
    #pragma unroll
    for (int mf = 0; mf < 2; ++mf) {
        const int row = wm * 64 + mf * 32 + l31;
        const unsigned m = (unsigned)(((row & 7) ^ ((row >> 3) & 7)) << 4);
        abx[mf] = (unsigned)(row * 128) | m;
    }
    #pragma unroll
    for (int nf = 0; nf < 2; ++nf) {
        const int row = wn * 64 + nf * 32 + l31;
        const unsigned m = (unsigned)(((row & 7) ^ ((row >> 3) & 7)) << 4);
        bbx[nf] = 0x4000u | (unsigned)(row * 128) | m;
    }

    // ---- staging: 1024 chunks (16B) per 128x64 matrix half; 4 per thread ----
    // chunk ci = tid + j*256: row r = ci>>3, slot s = ci&7; source column
    // applies the same involution: col = (s ^ m(r)) * 8 elements.
    unsigned goff[4];   // element offset r*K + col  (same for A and B tiles)
    unsigned adst[4];
    #pragma unroll
    for (int j = 0; j < 4; ++j) {
        const int ci = tid + j * 256;
        const int r = ci >> 3;
        const int mr = (r & 7) ^ ((r >> 3) & 7);
        const int col = ((ci & 7) ^ mr) << 3;
        goff[j] = (unsigned)(r * K + col);
        adst[j] = (unsigned)(ci * 16);
    }

    const unsigned short* aP = Xb + (size_t)arow0 * K;   // points at tile to stage
    const unsigned short* bP = Qb + (size_t)brow0 * K;

    // ---- prologue: stage tile 0 into buffer 0 ----
    #pragma unroll
    for (int j = 0; j < 4; ++j) {
        __builtin_amdgcn_global_load_lds(GLOBAL_CAST(aP + goff[j]), LDS_CAST(lds + adst[j]), 16, 0, 0);
        __builtin_amdgcn_global_load_lds(GLOBAL_CAST(bP + goff[j]), LDS_CAST(lds + (adst[j] | 0x4000u)), 16, 0, 0);
    }
    aP += BK; bP += BK;
    asm volatile("s_waitcnt vmcnt(0)" ::: "memory");
    __builtin_amdgcn_sched_barrier(0);
    __builtin_amdgcn_s_barrier();

    f32x16 acc[2][2] = {};
    bf16x8 aX[2], bX[2], aY[2], bY[2];

    #define RDSLICE(AV, BV, KS) {                                               \
        _Pragma("unroll")                                                       \
        for (int mf = 0; mf < 2; ++mf)                                          \
            AV[mf] = *(const bf16x8*)(lds + ((tb | abx[mf]) ^ ksel[KS]));       \
        _Pragma("unroll")                                                       \
        for (int nf = 0; nf < 2; ++nf)                                          \
            BV[nf] = *(const bf16x8*)(lds + ((tb | bbx[nf]) ^ ksel[KS])); }
    #define MFMA4(AV, BV)                                                       \
        _Pragma("unroll")                                                       \
        for (int mf = 0; mf < 2; ++mf)                                          \
            _Pragma("unroll")                                                   \
            for (int nf = 0; nf < 2; ++nf)                                      \
                acc[mf][nf] = __builtin_amdgcn_mfma_f32_32x32x16_bf16(          \
                    AV[mf], BV[nf], acc[mf][nf], 0, 0, 0);

    for (int t = 0; t < NT; ++t) {
        const unsigned tb = (unsigned)(t & 1) << 15;
        const unsigned ta = tb ^ 0x8000u;
        const bool doS = (t < NT - 1);

        // ================= section A =================
        if (doS) {
            #pragma unroll
            for (int j = 0; j < 4; ++j)
                __builtin_amdgcn_global_load_lds(GLOBAL_CAST(aP + goff[j]), LDS_CAST(lds + (ta | adst[j])), 16, 0, 0);
        }
        RDSLICE(aX, bX, 0)
        __builtin_amdgcn_s_setprio(1);
        MFMA4(aX, bX)
        __builtin_amdgcn_s_setprio(0);

        if (doS) {
            #pragma unroll
            for (int j = 0; j < 4; ++j)
                __builtin_amdgcn_global_load_lds(GLOBAL_CAST(bP + goff[j]), LDS_CAST(lds + (ta | adst[j] | 0x4000u)), 16, 0, 0);
        }
        RDSLICE(aY, bY, 1)
        __builtin_amdgcn_s_setprio(1);
        MFMA4(aY, bY)
        __builtin_amdgcn_s_setprio(0);

        __builtin_amdgcn_s_barrier();

        // ================= section B =================
        RDSLICE(aX, bX, 2)
        __builtin_amdgcn_s_setprio(1);
        MFMA4(aX, bX)
        __builtin_amdgcn_s_setprio(0);

        RDSLICE(aY, bY, 3)
        __builtin_amdgcn_s_setprio(1);
        MFMA4(aY, bY)
        __builtin_amdgcn_s_setprio(0);

        aP += BK; bP += BK;
        asm volatile("s_waitcnt vmcnt(0)" ::: "memory");
        __builtin_amdgcn_sched_barrier(0);
        __builtin_amdgcn_s_barrier();
    }
    #undef RDSLICE
    #undef MFMA4

    // epilogue: out = scale[n]*acc + bias[n]
    // C/D: col = lane&31, row = (reg&3) + 8*(reg>>2) + 4*(lane>>5)
    #pragma unroll
    for (int nf = 0; nf < 2; ++nf) {
        const int gn = brow0 + wn * 64 + nf * 32 + l31;
        const float sc = scale[gn];
        const float bs = bias[gn];
        #pragma unroll
        for (int mf = 0; mf < 2; ++mf) {
            const size_t gm0 = (size_t)arow0 + wm * 64 + mf * 32 + ((lane >> 5) << 2);
            #pragma unroll
            for (int reg = 0; reg < 16; ++reg) {
                const int row = (reg & 3) + ((reg >> 2) << 3);
                out[(gm0 + row) * (size_t)N + gn] = acc[mf][nf][reg] * sc + bs;
            }
        }
    }
}

// ---------------------------------------------------------------------------
// Fallback: fp32 smem-tiled GEMM, quantize on the fly.
// ---------------------------------------------------------------------------
__global__ __launch_bounds__(256) void fb_gemm_kernel(
    const float* __restrict__ X, const float* __restrict__ W,
    const float* __restrict__ scale, const float* __restrict__ bias,
    float* __restrict__ out, int M, int N, int K)
{
    __shared__ float xs[16][16];
    __shared__ float qs[16][17];
    const int tx = threadIdx.x & 15, ty = threadIdx.x >> 4;
    const int m = blockIdx.y * 16 + ty;
    const int n = blockIdx.x * 16 + tx;
    const int nrow = blockIdx.x * 16 + ty;
    const int mL = min(m, M - 1);
    const int nrowL = min(nrow, N - 1);
    const float thr = scale[nrowL] * 0.75f;
    float acc = 0.f;
    for (int k0 = 0; k0 < K; k0 += 16) {
        xs[ty][tx] = X[(size_t)mL * K + k0 + tx];
        const float w = W[(size_t)nrowL * K + k0 + tx];
        qs[ty][tx] = (w >= thr) ? 1.f : ((w <= -thr) ? -1.f : 0.f);
        __syncthreads();
        #pragma unroll
        for (int kk = 0; kk < 16; ++kk) acc += xs[ty][kk] * qs[tx][kk];
        __syncthreads();
    }
    if (m < M && n < N) out[(size_t)m * N + n] = scale[n] * acc + bias[n];
}

// ---------------------------------------------------------------------------
extern "C" void kernel_launch(void* const* d_in, const int* in_sizes, int n_in,
                              void* d_out, int out_size, void* d_ws, size_t ws_size,
                              hipStream_t stream)
{
    const float* x    = (const float*)d_in[0];
    const float* w    = (const float*)d_in[1];
    const float* bias = (const float*)d_in[2];
    float* out = (float*)d_out;

    const int N = in_sizes[2];             // OUT
    const int K = in_sizes[1] / N;         // IN
    const int M = in_sizes[0] / K;         // B

    const size_t scaleBytes = (size_t)N * sizeof(float);
    const size_t qOff = (scaleBytes + 255) & ~(size_t)255;
    const size_t xOff = qOff + (size_t)N * K * sizeof(unsigned short);
    const size_t need = xOff + (size_t)M * K * sizeof(unsigned short);

    float* scale = (float*)d_ws;

    const bool fast = (ws_size >= need) &&
                      (M % BM == 0) && (N % BN == 0) && (K % BK == 0) &&
                      (K / BK >= 2) &&
                      (((M / BM) * (N / BN)) % 8 == 0);

    if (fast) {
        unsigned short* q  = (unsigned short*)((char*)d_ws + qOff);
        unsigned short* xb = (unsigned short*)((char*)d_ws + xOff);

        scale_quant_kernel<<<N, 256, 0, stream>>>(w, scale, q, K);

        const long nx = (long)M * K;
        const int cvtBlocks = (int)((nx + 2047) / 2048);
        convert_x_kernel<<<cvtBlocks, 256, 0, stream>>>(x, xb, nx);

        const int grid = (M / BM) * (N / BN);
        gemm128_kernel<<<grid, 256, 0, stream>>>(xb, q, scale, bias, out, M, N, K);
    } else {
        scale_quant_kernel<<<N, 256, 0, stream>>>(w, scale, nullptr, K);
        dim3 g((N + 15) / 16, (M + 15) / 16);
        fb_gemm_kernel<<<g, 256, 0, stream>>>(x, w, scale, bias, out, M, N, K);
    }
}

// Round 10
// 298.791 us; speedup vs baseline: 1.1885x; 1.1885x over previous
//
#include <hip/hip_runtime.h>
#include <hip/hip_bf16.h>

typedef __attribute__((ext_vector_type(8))) short bf16x8;
typedef __attribute__((ext_vector_type(4))) float f32x4;

#define GLOBAL_CAST(p) (const __attribute__((address_space(1))) void*)(p)
#define LDS_CAST(p)    (__attribute__((address_space(3))) void*)(p)

static __device__ __forceinline__ unsigned short f2bf(float f) {
    union { float f; unsigned int u; } v; v.f = f;
    unsigned int u = v.u;
    unsigned int r = (u + 0x7FFFu + ((u >> 16) & 1u)) >> 16;   // RNE
    return (unsigned short)r;
}

// ---------------------------------------------------------------------------
// Kernel 1: per-row scale = max(mean(|w|), eps); q = ternary(w) as bf16 bits.
// ---------------------------------------------------------------------------
__global__ __launch_bounds__(256) void scale_quant_kernel(
    const float* __restrict__ w, float* __restrict__ scale,
    unsigned short* __restrict__ q, int K)
{
    const int row = blockIdx.x;
    const int tid = threadIdx.x;
    const float* wrow = w + (size_t)row * K;

    float s = 0.f;
    const int nvec = K >> 2;
    const float4* wv = (const float4*)wrow;
    for (int i = tid; i < nvec; i += blockDim.x) {
        float4 v = wv[i];
        s += fabsf(v.x) + fabsf(v.y) + fabsf(v.z) + fabsf(v.w);
    }
    #pragma unroll
    for (int off = 32; off > 0; off >>= 1) s += __shfl_down(s, off);

    __shared__ float red[4];
    const int lane = tid & 63, wid = tid >> 6;
    if (lane == 0) red[wid] = s;
    __syncthreads();
    const float total = red[0] + red[1] + red[2] + red[3];
    const float sc = fmaxf(total / (float)K, 1e-6f);
    const float thr = sc * 0.75f;
    if (tid == 0) scale[row] = sc;

    if (q != nullptr) {
        ushort4* qv = (ushort4*)(q + (size_t)row * K);
        for (int i = tid; i < nvec; i += blockDim.x) {
            float4 v = wv[i];
            ushort4 o;
            o.x = (v.x >= thr) ? 0x3F80u : ((v.x <= -thr) ? 0xBF80u : 0u);
            o.y = (v.y >= thr) ? 0x3F80u : ((v.y <= -thr) ? 0xBF80u : 0u);
            o.z = (v.z >= thr) ? 0x3F80u : ((v.z <= -thr) ? 0xBF80u : 0u);
            o.w = (v.w >= thr) ? 0x3F80u : ((v.w <= -thr) ? 0xBF80u : 0u);
            qv[i] = o;
        }
    }
}

// ---------------------------------------------------------------------------
// Kernel 2: x fp32 -> bf16 (RNE), 8 elems/thread.
// ---------------------------------------------------------------------------
__global__ __launch_bounds__(256) void convert_x_kernel(
    const float* __restrict__ x, unsigned short* __restrict__ xb, long n)
{
    long i = ((long)blockIdx.x * blockDim.x + threadIdx.x) * 8;
    if (i + 8 > n) return;
    float4 a = *(const float4*)(x + i);
    float4 b = *(const float4*)(x + i + 4);
    ushort4 lo, hi;
    lo.x = f2bf(a.x); lo.y = f2bf(a.y); lo.z = f2bf(a.z); lo.w = f2bf(a.w);
    hi.x = f2bf(b.x); hi.y = f2bf(b.y); hi.z = f2bf(b.z); hi.w = f2bf(b.w);
    *(ushort4*)(xb + i)     = lo;
    *(ushort4*)(xb + i + 4) = hi;
}

// ---------------------------------------------------------------------------
// Kernel 3: 256x256 bf16 GEMM, 16x16x32 MFMA, depth-3 region pipeline.
//   out[m][n] = scale[n] * sum_k Xb[m][k]*Qb[n][k] + bias[n]
// 512 thr = 8 waves (2M x 4N); per-wave 128x64 out = acc[8][4].
// LDS 128 KiB, 4 CONTIGUOUS regions of {A 16K | B 16K}:
//   A region(buf,kh2) at buf*64K + kh2*16K; B at +32K. Region = one k-half
//   (32 elems) of one K-tile: [256 rows][4 slots x 16B], row stride 64 B.
// Staging (rule-21-safe): LDS dest LINEAR (base + ci*16, ci = tid / tid+512);
//   global source column pre-swizzled: slot s of row r holds local chunk
//   s ^ ((r>>1)&3)  -> read slot = kh ^ ((row>>1)&3).
// Phase phi (= 2t+cc, k = phi*32):
//   stage region phi+3 (4 gload_lds) | 12 ds_read_b128 of region phi |
//   32 MFMA (setprio) | vmcnt(8) [= 2 regions in flight; region phi+1
//   guaranteed landed] | sched_barrier(0) | s_barrier.
// Steady state never drains vmcnt. Overwrite target = region phi-1 (mod 4),
// whose reads completed (consumed by MFMA) before the previous barrier.
// ---------------------------------------------------------------------------
#define BM 256
#define BN 256
#define BK 64

__global__ __launch_bounds__(512, 2) void gemm256_kernel(
    const unsigned short* __restrict__ Xb,   // [M][K] bf16 bits
    const unsigned short* __restrict__ Qb,   // [N][K] bf16 bits
    const float* __restrict__ scale,
    const float* __restrict__ bias,
    float* __restrict__ out, int M, int N, int K)
{
    __shared__ __align__(16) char lds[131072];

    const int tid  = threadIdx.x;
    const int lane = tid & 63;
    const int wid  = tid >> 6;       // 0..7
    const int wm   = wid >> 2;       // 0..1  (M half of tile)
    const int wn   = wid & 3;        // 0..3  (N quarter)
    const int kh   = lane >> 4;      // 0..3
    const int lr   = lane & 15;

    // XCD-bijective swizzle (grid % 8 == 0 guaranteed by host gate)
    int bid = blockIdx.x;
    const int nwg = gridDim.x;
    if ((nwg & 7) == 0) { const int cpx = nwg >> 3; bid = (bid & 7) * cpx + (bid >> 3); }
    const int nbn = N / BN;
    const int tm = bid / nbn, tn = bid % nbn;
    const int arow0 = tm * BM;
    const int brow0 = tn * BN;
    const int NT = K / BK;
    const int PHI = 2 * NT;

    // ---- LDS read offsets (region-base-relative); addr = dxr | off ----
    unsigned aoff[8], boff[4];
    #pragma unroll
    for (int mf = 0; mf < 8; ++mf) {
        const int row = wm * 128 + mf * 16 + lr;
        aoff[mf] = (unsigned)(row * 64 + ((kh ^ ((row >> 1) & 3)) << 4));
    }
    #pragma unroll
    for (int nf = 0; nf < 4; ++nf) {
        const int row = wn * 64 + nf * 16 + lr;
        boff[nf] = 0x8000u | (unsigned)(row * 64 + ((kh ^ ((row >> 1) & 3)) << 4));
    }

    // ---- staging: ci0 = tid (rows 0..127), ci1 = tid+512 (rows 128..255) ----
    const int r0 = tid >> 2;
    const int s0 = tid & 3;
    const int scol = (s0 ^ ((r0 >> 1) & 3)) << 3;   // same for ci1 (r+128)
    const unsigned sdA0 = (unsigned)(tid * 16);
    const unsigned sdA1 = (unsigned)((tid + 512) * 16);
    const unsigned sdB0 = 0x8000u | sdA0;
    const unsigned sdB1 = 0x8000u | sdA1;

    const unsigned short* aBase0 = Xb + (size_t)(arow0 + r0) * K + scol;
    const unsigned short* aBase1 = Xb + (size_t)(arow0 + r0 + 128) * K + scol;
    const unsigned short* bBase0 = Qb + (size_t)(brow0 + r0) * K + scol;
    const unsigned short* bBase1 = Qb + (size_t)(brow0 + r0 + 128) * K + scol;

    // ---- prologue: stage regions 0,1,2 ----
    #pragma unroll
    for (int rho = 0; rho < 3; ++rho) {
        const unsigned dxs = (unsigned)((rho & 1) << 14) | ((unsigned)((rho >> 1) & 1) << 16);
        const int ke = rho * 32;
        __builtin_amdgcn_global_load_lds(GLOBAL_CAST(aBase0 + ke), LDS_CAST(lds + (dxs | sdA0)), 16, 0, 0);
        __builtin_amdgcn_global_load_lds(GLOBAL_CAST(aBase1 + ke), LDS_CAST(lds + (dxs | sdA1)), 16, 0, 0);
        __builtin_amdgcn_global_load_lds(GLOBAL_CAST(bBase0 + ke), LDS_CAST(lds + (dxs | sdB0)), 16, 0, 0);
        __builtin_amdgcn_global_load_lds(GLOBAL_CAST(bBase1 + ke), LDS_CAST(lds + (dxs | sdB1)), 16, 0, 0);
    }
    const unsigned short* aS0 = aBase0 + 96;   // region 3 onward
    const unsigned short* aS1 = aBase1 + 96;
    const unsigned short* bS0 = bBase0 + 96;
    const unsigned short* bS1 = bBase1 + 96;

    asm volatile("s_waitcnt vmcnt(8)" ::: "memory");
    __builtin_amdgcn_sched_barrier(0);
    __builtin_amdgcn_s_barrier();

    f32x4 acc[8][4] = {};

    for (int t = 0; t < NT; ++t) {
        #pragma unroll
        for (int cc = 0; cc < 2; ++cc) {
            const int phi = 2 * t + cc;
            // read-region base: buf = t&1, kh2 = cc
            const unsigned dxr = ((unsigned)cc << 14) | ((unsigned)(t & 1) << 16);

            // ---- stage region phi+3 ----
            if (phi < PHI - 3) {
                const unsigned dxs = (cc == 0)
                    ? ((1u << 14) | ((unsigned)((t & 1) ^ 1) << 16))
                    : ((unsigned)(t & 1) << 16);
                __builtin_amdgcn_global_load_lds(GLOBAL_CAST(aS0), LDS_CAST(lds + (dxs | sdA0)), 16, 0, 0);
                __builtin_amdgcn_global_load_lds(GLOBAL_CAST(aS1), LDS_CAST(lds + (dxs | sdA1)), 16, 0, 0);
                __builtin_amdgcn_global_load_lds(GLOBAL_CAST(bS0), LDS_CAST(lds + (dxs | sdB0)), 16, 0, 0);
                __builtin_amdgcn_global_load_lds(GLOBAL_CAST(bS1), LDS_CAST(lds + (dxs | sdB1)), 16, 0, 0);
                aS0 += 32; aS1 += 32; bS0 += 32; bS1 += 32;
            }

            // ---- 12 ds_reads of region phi ----
            bf16x8 a[8], b[4];
            #pragma unroll
            for (int mf = 0; mf < 8; ++mf)
                a[mf] = *(const bf16x8*)(lds + (dxr | aoff[mf]));
            #pragma unroll
            for (int nf = 0; nf < 4; ++nf)
                b[nf] = *(const bf16x8*)(lds + (dxr | boff[nf]));

            // ---- 32 MFMA ----
            __builtin_amdgcn_s_setprio(1);
            #pragma unroll
            for (int mf = 0; mf < 8; ++mf)
                #pragma unroll
                for (int nf = 0; nf < 4; ++nf)
                    acc[mf][nf] = __builtin_amdgcn_mfma_f32_16x16x32_bf16(
                        a[mf], b[nf], acc[mf][nf], 0, 0, 0);
            __builtin_amdgcn_s_setprio(0);

            // ---- counted wait + barrier (one pin per phase) ----
            if (phi < PHI - 3)       { asm volatile("s_waitcnt vmcnt(8)" ::: "memory"); }
            else if (phi == PHI - 3) { asm volatile("s_waitcnt vmcnt(4)" ::: "memory"); }
            else                     { asm volatile("s_waitcnt vmcnt(0)" ::: "memory"); }
            __builtin_amdgcn_sched_barrier(0);
            __builtin_amdgcn_s_barrier();
        }
    }

    // epilogue: out = scale[n]*acc + bias[n]; D layout col=lane&15, row=(lane>>4)*4+r
    #pragma unroll
    for (int nf = 0; nf < 4; ++nf) {
        const int gn = brow0 + wn * 64 + nf * 16 + lr;
        const float sc = scale[gn];
        const float bs = bias[gn];
        #pragma unroll
        for (int mf = 0; mf < 8; ++mf) {
            const size_t gm = (size_t)arow0 + wm * 128 + mf * 16 + kh * 4;
            #pragma unroll
            for (int r = 0; r < 4; ++r)
                out[(gm + r) * (size_t)N + gn] = acc[mf][nf][r] * sc + bs;
        }
    }
}

// ---------------------------------------------------------------------------
// Fallback: fp32 smem-tiled GEMM, quantize on the fly.
// ---------------------------------------------------------------------------
__global__ __launch_bounds__(256) void fb_gemm_kernel(
    const float* __restrict__ X, const float* __restrict__ W,
    const float* __restrict__ scale, const float* __restrict__ bias,
    float* __restrict__ out, int M, int N, int K)
{
    __shared__ float xs[16][16];
    __shared__ float qs[16][17];
    const int tx = threadIdx.x & 15, ty = threadIdx.x >> 4;
    const int m = blockIdx.y * 16 + ty;
    const int n = blockIdx.x * 16 + tx;
    const int nrow = blockIdx.x * 16 + ty;
    const int mL = min(m, M - 1);
    const int nrowL = min(nrow, N - 1);
    const float thr = scale[nrowL] * 0.75f;
    float acc = 0.f;
    for (int k0 = 0; k0 < K; k0 += 16) {
        xs[ty][tx] = X[(size_t)mL * K + k0 + tx];
        const float w = W[(size_t)nrowL * K + k0 + tx];
        qs[ty][tx] = (w >= thr) ? 1.f : ((w <= -thr) ? -1.f : 0.f);
        __syncthreads();
        #pragma unroll
        for (int kk = 0; kk < 16; ++kk) acc += xs[ty][kk] * qs[tx][kk];
        __syncthreads();
    }
    if (m < M && n < N) out[(size_t)m * N + n] = scale[n] * acc + bias[n];
}

// ---------------------------------------------------------------------------
extern "C" void kernel_launch(void* const* d_in, const int* in_sizes, int n_in,
                              void* d_out, int out_size, void* d_ws, size_t ws_size,
                              hipStream_t stream)
{
    const float* x    = (const float*)d_in[0];
    const float* w    = (const float*)d_in[1];
    const float* bias = (const float*)d_in[2];
    float* out = (float*)d_out;

    const int N = in_sizes[2];             // OUT
    const int K = in_sizes[1] / N;         // IN
    const int M = in_sizes[0] / K;         // B

    const size_t scaleBytes = (size_t)N * sizeof(float);
    const size_t qOff = (scaleBytes + 255) & ~(size_t)255;
    const size_t xOff = qOff + (size_t)N * K * sizeof(unsigned short);
    const size_t need = xOff + (size_t)M * K * sizeof(unsigned short);

    float* scale = (float*)d_ws;

    const bool fast = (ws_size >= need) &&
                      (M % BM == 0) && (N % BN == 0) && (K % BK == 0) &&
                      (K / BK >= 4) &&
                      (((M / BM) * (N / BN)) % 8 == 0);

    if (fast) {
        unsigned short* q  = (unsigned short*)((char*)d_ws + qOff);
        unsigned short* xb = (unsigned short*)((char*)d_ws + xOff);

        scale_quant_kernel<<<N, 256, 0, stream>>>(w, scale, q, K);

        const long nx = (long)M * K;
        const int cvtBlocks = (int)((nx + 2047) / 2048);
        convert_x_kernel<<<cvtBlocks, 256, 0, stream>>>(x, xb, nx);

        const int grid = (M / BM) * (N / BN);
        gemm256_kernel<<<grid, 512, 0, stream>>>(xb, q, scale, bias, out, M, N, K);
    } else {
        scale_quant_kernel<<<N, 256, 0, stream>>>(w, scale, nullptr, K);
        dim3 g((N + 15) / 16, (M + 15) / 16);
        fb_gemm_kernel<<<g, 256, 0, stream>>>(x, w, scale, bias, out, M, N, K);
    }
}